// Round 12
// baseline (94.298 us; speedup 1.0000x reference)
//
#include <hip/hip_runtime.h>

// Problem constants
#define BATCH 1024
#define NIN   512
#define NOUT  512
#define NB    11
// K-dim layout: i*12 + j ; j in [0,11) = basis k, j==11 = silu/w column
#define KDIM  (NIN * 12)          // 6144
#define SPLITS 16
#define IPS    (NIN / SPLITS)     // 32 i per split
#define LDW    104                // padded LDS row (96 + 8) — conflict-free b128

typedef short bf16x8 __attribute__((ext_vector_type(8)));
typedef float f32x4  __attribute__((ext_vector_type(4)));
typedef unsigned short ushort8 __attribute__((ext_vector_type(8)));

__device__ __forceinline__ unsigned short f2bf(float f) {
  unsigned u = __float_as_uint(f);
  u += 0x7fff + ((u >> 16) & 1);   // RNE to bf16
  return (unsigned short)(u >> 16);
}
__device__ __forceinline__ float bf2f(unsigned short h) {
  return __uint_as_float((unsigned)h << 16);
}

// K1 prep: 256 blocks, 8i x 128o tiles (R7-proven, coalesced).
__global__ __launch_bounds__(256) void k_prep(const float* __restrict__ c,
                                              const float* __restrict__ w,
                                              unsigned short* __restrict__ Bt) {
  __shared__ float          ws_[8 * 128];     // 4 KB
  __shared__ unsigned short sbt[128 * 96];    // 24 KB, [o_local][i_local*12+j]
  int tid = threadIdx.x;
  int bc  = blockIdx.x;
  int i0  = (bc >> 2) * 8;
  int o0  = (bc & 3) * 128;
  {
    int r = tid >> 5, oq = (tid & 31) * 4;
    *(f32x4*)&ws_[r * 128 + oq] = *(const f32x4*)&w[(size_t)(i0 + r) * NOUT + o0 + oq];
  }
  __syncthreads();
  for (int n = 0; n < 11; ++n) {
    int ch  = n * 256 + tid;                   // 2816 float4 chunks
    int il  = ch / 352;
    int off = (ch - il * 352) * 4;             // [0,1408)
    f32x4 cv = *(const f32x4*)&c[(size_t)(i0 + il) * (NIN * NB) + (size_t)o0 * NB + off];
#pragma unroll
    for (int e = 0; e < 4; ++e) {
      int t  = off + e;
      int op = t / 11;
      int k  = t - op * 11;
      sbt[op * 96 + il * 12 + k] = f2bf(cv[e] * ws_[il * 128 + op]);
    }
  }
  {
    int il = tid >> 5, oq = (tid & 31) * 4;
#pragma unroll
    for (int e = 0; e < 4; ++e)
      sbt[(oq + e) * 96 + il * 12 + 11] = f2bf(ws_[il * 128 + oq + e]);
  }
  __syncthreads();
  for (int n = 0; n < 6; ++n) {
    int ch = n * 256 + tid;                    // 1536 chunks
    int op = ch / 12, q = ch - op * 12;
    *(ushort8*)&Bt[(size_t)(o0 + op) * KDIM + i0 * 12 + q * 8] =
        *(const ushort8*)&sbt[op * 96 + q * 8];
  }
}

// A-gen from a prefetched x-vector into an LDS buffer (closed-form cubic)
__device__ __forceinline__ void a_gen(f32x4 xv, unsigned short* __restrict__ As,
                                      int tid) {
  int bl  = tid >> 1;
  int il0 = (tid & 1) * 4;
  unsigned short* arow = &As[bl * LDW];
#pragma unroll
  for (int q = 0; q < 4; ++q) {
    int col = (il0 + q) * 12;
    *(unsigned long long*)&arow[col]     = 0ULL;
    *(unsigned long long*)&arow[col + 4] = 0ULL;
    *(unsigned long long*)&arow[col + 8] = 0ULL;
    float xq = xv[q];
    float um = (xq + 5.25f) * (1.0f / 0.75f);
    int   m  = (int)floorf(um);
    if (m >= 0 && m <= 13) {
      float u  = um - (float)m;
      float u2 = u * u, u3 = u2 * u;
      float omu = 1.0f - u;
      float w3 = u3 * (1.0f / 6.0f);
      float w2 = (-3.0f*u3 + 3.0f*u2 + 3.0f*u + 1.0f) * (1.0f/6.0f);
      float w1 = (3.0f*u3 - 6.0f*u2 + 4.0f) * (1.0f/6.0f);
      float w0 = omu * omu * omu * (1.0f / 6.0f);
      int j0 = m - 3;
      if (j0 >= 0 && j0 <= 10)         arow[col + j0]     = f2bf(w0);
      if (j0 + 1 >= 0 && j0 + 1 <= 10) arow[col + j0 + 1] = f2bf(w1);
      if (j0 + 2 >= 0 && j0 + 2 <= 10) arow[col + j0 + 2] = f2bf(w2);
      if (m <= 10)                     arow[col + m]      = f2bf(w3);
    }
    float sig = 1.0f / (1.0f + __expf(-xq));
    arow[col + 11] = f2bf(xq * sig);
  }
}

// K2: fused basis-gen + split-K GEMM -> bf16 partials.
// Restructured K-loop: B fragments read DIRECTLY from global (each
// global_load_dwordx4 = 16 rows x one fully-consumed 64B line; L1-resident
// within an iter) interleaved 1:1 with MFMAs — no barrier in that path.
// A double-buffered in LDS (2 x 26.6 KB, same footprint as before):
// a_gen(t+1) overlaps MFMA(t); ONE barrier per iteration.
__global__ __launch_bounds__(256) void k_fused(const float* __restrict__ x,
                                               const unsigned short* __restrict__ Bt,
                                               unsigned short* __restrict__ part,
                                               float* __restrict__ out,
                                               int splits, int ipersplit) {
  __shared__ unsigned short As2[2][128 * LDW];   // 53.2 KB total
  const int tid  = threadIdx.x;
  const int lane = tid & 63, wave = tid >> 6;
  const int wr = wave >> 1, wc = wave & 1;
  const int mbase = blockIdx.x * 128, nbase = blockIdx.y * 128;
  const int split = blockIdx.z;
  const int istart = split * ipersplit;

  f32x4 acc[4][4] = {};
  const int mrow = lane & 15;
  const int kq   = (lane >> 4) * 8;

  // B row pointers: lane reads its own fragment rows straight from global
  const unsigned short* bgp[4];
#pragma unroll
  for (int nt = 0; nt < 4; ++nt)
    bgp[nt] = &Bt[(size_t)(nbase + wc * 64 + nt * 16 + mrow) * KDIM + kq];

  // x prefetch addressing
  const float* xg = &x[(size_t)(mbase + (tid >> 1)) * NIN + (tid & 1) * 4];

  const int iters = ipersplit / 8;
  // prologue: stage iter 0 into buf 0
  f32x4 xv = *(const f32x4*)&xg[istart];
  a_gen(xv, As2[0], tid);
  if (iters > 1) xv = *(const f32x4*)&xg[istart + 8];
  __syncthreads();

  for (int it = 0; it < iters; ++it) {
    const int cur = it & 1;
    const int ib  = istart + it * 8;
    // stage NEXT iter's A into the other buffer (overlaps this iter's MFMA)
    if (it + 1 < iters) {
      a_gen(xv, As2[cur ^ 1], tid);
      if (it + 2 < iters) xv = *(const f32x4*)&xg[ib + 16];
    }

    const unsigned short* asb = As2[cur];
    const int kBase = ib * 12;
#pragma unroll
    for (int ks = 0; ks < 96; ks += 32) {
      bf16x8 bfr[4], af[4];
#pragma unroll
      for (int nt = 0; nt < 4; ++nt)
        bfr[nt] = *(const bf16x8*)&bgp[nt][kBase + ks];   // global, via L1
#pragma unroll
      for (int mt = 0; mt < 4; ++mt)
        af[mt] = *(const bf16x8*)&asb[(wr * 64 + mt * 16 + mrow) * LDW + ks + kq];
#pragma unroll
      for (int mt = 0; mt < 4; ++mt)
#pragma unroll
        for (int nt = 0; nt < 4; ++nt)
          acc[mt][nt] = __builtin_amdgcn_mfma_f32_16x16x32_bf16(af[mt], bfr[nt], acc[mt][nt], 0, 0, 0);
    }
    if (it + 1 < iters) __syncthreads();   // protects As2[cur^1] for next iter
  }

  // epilogue: C/D layout col = lane&15, row = (lane>>4)*4 + reg
  const int rq = (lane >> 4) * 4;
  if (splits == 1) {
#pragma unroll
    for (int mt = 0; mt < 4; ++mt)
#pragma unroll
      for (int nt = 0; nt < 4; ++nt) {
        int colg = nbase + wc * 64 + nt * 16 + mrow;
#pragma unroll
        for (int r = 0; r < 4; ++r) {
          int rowg = mbase + wr * 64 + mt * 16 + rq + r;
          out[(size_t)rowg * NOUT + colg] = acc[mt][nt][r];
        }
      }
    return;
  }
#pragma unroll
  for (int mt = 0; mt < 4; ++mt)
#pragma unroll
    for (int nt = 0; nt < 4; ++nt) {
      int colg = nbase + wc * 64 + nt * 16 + mrow;
#pragma unroll
      for (int r = 0; r < 4; ++r) {
        int rowg = mbase + wr * 64 + mt * 16 + rq + r;
        part[((size_t)split * BATCH + rowg) * NOUT + colg] = f2bf(acc[mt][nt][r]);
      }
    }
}

// K3: out = sum over SPLITS bf16 partials (coalesced ushort8 loads)
__global__ __launch_bounds__(256) void k_reduce(const unsigned short* __restrict__ part,
                                                float* __restrict__ out) {
  int t = blockIdx.x * 256 + threadIdx.x;  // ushort8 index, 65536 total
  const ushort8* pv = (const ushort8*)part;
  float s[8] = {};
#pragma unroll
  for (int sp = 0; sp < SPLITS; ++sp) {
    ushort8 v = pv[(size_t)sp * (BATCH * NOUT / 8) + t];
#pragma unroll
    for (int e = 0; e < 8; ++e) s[e] += bf2f(v[e]);
  }
  f32x4 lo = { s[0], s[1], s[2], s[3] };
  f32x4 hi = { s[4], s[5], s[6], s[7] };
  ((f32x4*)out)[t * 2]     = lo;
  ((f32x4*)out)[t * 2 + 1] = hi;
}

extern "C" void kernel_launch(void* const* d_in, const int* in_sizes, int n_in,
                              void* d_out, int out_size, void* d_ws, size_t ws_size,
                              hipStream_t stream) {
  const float* x = (const float*)d_in[0];
  const float* c = (const float*)d_in[1];
  const float* w = (const float*)d_in[2];
  float* out = (float*)d_out;

  unsigned short* Bt = (unsigned short*)d_ws;
  size_t off_part = (size_t)NOUT * KDIM * 2;                 // 6.3 MB
  unsigned short* part = (unsigned short*)((char*)d_ws + off_part);
  size_t need = off_part + (size_t)SPLITS * BATCH * NOUT * 2;

  k_prep<<<dim3(256), 256, 0, stream>>>(c, w, Bt);
  if (ws_size >= need) {
    k_fused<<<dim3(8, 4, SPLITS), 256, 0, stream>>>(x, Bt, part, out, SPLITS, IPS);
    k_reduce<<<dim3((BATCH * NOUT / 8) / 256), 256, 0, stream>>>(part, out);
  } else {
    // fallback: single-pass straight to out (needs only Bt in ws)
    k_fused<<<dim3(8, 4, 1), 256, 0, stream>>>(x, Bt, part, out, 1, NIN);
  }
}

// Round 13
// 88.760 us; speedup vs baseline: 1.0624x; 1.0624x over previous
//
#include <hip/hip_runtime.h>

// Problem constants
#define BATCH 1024
#define NIN   512
#define NOUT  512
#define NB    11
// K-dim layout: i*12 + j ; j in [0,11) = basis k, j==11 = silu/w column
#define KDIM  (NIN * 12)          // 6144
#define SPLITS 16
#define IPS    (NIN / SPLITS)     // 32 i per split
#define LDW    104                // padded LDS row (96 + 8) — R7/R11-proven

typedef short bf16x8 __attribute__((ext_vector_type(8)));
typedef float f32x4  __attribute__((ext_vector_type(4)));
typedef unsigned short ushort8 __attribute__((ext_vector_type(8)));

__device__ __forceinline__ unsigned short f2bf(float f) {
  unsigned u = __float_as_uint(f);
  u += 0x7fff + ((u >> 16) & 1);   // RNE to bf16
  return (unsigned short)(u >> 16);
}
__device__ __forceinline__ float bf2f(unsigned short h) {
  return __uint_as_float((unsigned)h << 16);
}

// K1 prep: 512 blocks (2/CU), 4i x 128o tiles — geometry validated in R10 phase 1.
// Bt[o][i*12+k] = bf16(c[i][o][k] * w[i][o]) for k<11 ; Bt[o][i*12+11] = bf16(w[i][o]).
__global__ __launch_bounds__(256) void k_prep(const float* __restrict__ c,
                                              const float* __restrict__ w,
                                              unsigned short* __restrict__ Bt) {
  __shared__ float          ws_[4 * 128];     // 2 KB
  __shared__ unsigned short sbt[128 * 48];    // 12 KB, [o_local][i_local*12+j]
  int tid = threadIdx.x;
  int bc  = blockIdx.x;
  int i0  = (bc >> 2) * 4;          // 128 i-tiles
  int o0  = (bc & 3) * 128;         // 4 o-tiles
  if (tid < 128) {
    int il = tid >> 5, oq = (tid & 31) * 4;
    *(f32x4*)&ws_[il * 128 + oq] = *(const f32x4*)&w[(size_t)(i0 + il) * NOUT + o0 + oq];
  }
  __syncthreads();
  // c: 4 i x 1408 contiguous floats; scale by w; scatter to [o][i*12+k]
  for (int n = 0; n < 6; ++n) {
    int ch = n * 256 + tid;                    // 1408 float4 chunks
    if (ch < 1408) {
      int il  = ch / 352;
      int off = (ch - il * 352) * 4;           // [0,1408)
      f32x4 cv = *(const f32x4*)&c[(size_t)(i0 + il) * (NIN * NB) + (size_t)o0 * NB + off];
#pragma unroll
      for (int e = 0; e < 4; ++e) {
        int t  = off + e;
        int op = t / 11;
        int k  = t - op * 11;
        sbt[op * 48 + il * 12 + k] = f2bf(cv[e] * ws_[il * 128 + op]);
      }
    }
  }
  // silu col j=11: 512 entries
#pragma unroll
  for (int e = 0; e < 2; ++e) {
    int idx = e * 256 + tid;
    int op = idx >> 2, il = idx & 3;
    sbt[op * 48 + il * 12 + 11] = f2bf(ws_[il * 128 + op]);
  }
  __syncthreads();
  // writeout: 128 o x 6 16B chunks = 768
  for (int n = 0; n < 3; ++n) {
    int ch = n * 256 + tid;
    int op = ch / 6, q = ch - op * 6;
    *(ushort8*)&Bt[(size_t)(o0 + op) * KDIM + i0 * 12 + q * 8] =
        *(const ushort8*)&sbt[op * 48 + q * 8];
  }
}

// A-gen from a prefetched x-vector into LDS (basis + silu, closed-form cubic)
__device__ __forceinline__ void a_gen(f32x4 xv, unsigned short* __restrict__ As,
                                      int tid) {
  int bl  = tid >> 1;
  int il0 = (tid & 1) * 4;
  unsigned short* arow = &As[bl * LDW];
#pragma unroll
  for (int q = 0; q < 4; ++q) {
    int col = (il0 + q) * 12;
    *(unsigned long long*)&arow[col]     = 0ULL;
    *(unsigned long long*)&arow[col + 4] = 0ULL;
    *(unsigned long long*)&arow[col + 8] = 0ULL;
    float xq = xv[q];
    float um = (xq + 5.25f) * (1.0f / 0.75f);
    int   m  = (int)floorf(um);
    if (m >= 0 && m <= 13) {
      float u  = um - (float)m;
      float u2 = u * u, u3 = u2 * u;
      float omu = 1.0f - u;
      float w3 = u3 * (1.0f / 6.0f);
      float w2 = (-3.0f*u3 + 3.0f*u2 + 3.0f*u + 1.0f) * (1.0f/6.0f);
      float w1 = (3.0f*u3 - 6.0f*u2 + 4.0f) * (1.0f/6.0f);
      float w0 = omu * omu * omu * (1.0f / 6.0f);
      int j0 = m - 3;
      if (j0 >= 0 && j0 <= 10)         arow[col + j0]     = f2bf(w0);
      if (j0 + 1 >= 0 && j0 + 1 <= 10) arow[col + j0 + 1] = f2bf(w1);
      if (j0 + 2 >= 0 && j0 + 2 <= 10) arow[col + j0 + 2] = f2bf(w2);
      if (m <= 10)                     arow[col + m]      = f2bf(w3);
    }
    float sig = 1.0f / (1.0f + __expf(-xq));
    arow[col + 11] = f2bf(xq * sig);
  }
}

// K2: fused basis-gen + split-K GEMM -> bf16 partials. R11-exact: LDS-staged
// A (generated) and B, register-prefetched next-iter staging so global loads
// retire during the MFMA phase.
__global__ __launch_bounds__(256) void k_fused(const float* __restrict__ x,
                                               const unsigned short* __restrict__ Bt,
                                               unsigned short* __restrict__ part,
                                               float* __restrict__ out,
                                               int splits, int ipersplit) {
  __shared__ unsigned short As[128 * LDW];   // 26.6 KB
  __shared__ unsigned short Bs[128 * LDW];   // 26.6 KB
  const int tid  = threadIdx.x;
  const int lane = tid & 63, wave = tid >> 6;
  const int wr = wave >> 1, wc = wave & 1;
  const int mbase = blockIdx.x * 128, nbase = blockIdx.y * 128;
  const int split = blockIdx.z;
  const int istart = split * ipersplit;

  f32x4 acc[4][4] = {};
  const int mrow = lane & 15;
  const int kq   = (lane >> 4) * 8;

  // staging-address precompute
  const float* xg = &x[(size_t)(mbase + (tid >> 1)) * NIN + (tid & 1) * 4];
  int brow[6], bcg[6];
  const unsigned short* bg[6];
#pragma unroll
  for (int n = 0; n < 6; ++n) {
    int ch  = n * 256 + tid;
    brow[n] = ch / 12;
    bcg[n]  = ch - brow[n] * 12;
    bg[n]   = &Bt[(size_t)(nbase + brow[n]) * KDIM + bcg[n] * 8];
  }

  const int iters = ipersplit / 8;
  // prologue: prefetch iter 0
  f32x4   xv = *(const f32x4*)&xg[istart];
  ushort8 bv[6];
#pragma unroll
  for (int n = 0; n < 6; ++n) bv[n] = *(const ushort8*)&bg[n][(size_t)istart * 12];

  for (int it = 0; it < iters; ++it) {
    int ib = istart + it * 8;
    a_gen(xv, As, tid);
#pragma unroll
    for (int n = 0; n < 6; ++n)
      *(ushort8*)&Bs[brow[n] * LDW + bcg[n] * 8] = bv[n];

    // issue next-iter loads NOW — they retire during the MFMA phase
    if (it + 1 < iters) {
      int ibn = ib + 8;
      xv = *(const f32x4*)&xg[ibn];
#pragma unroll
      for (int n = 0; n < 6; ++n) bv[n] = *(const ushort8*)&bg[n][(size_t)ibn * 12];
    }
    __syncthreads();

#pragma unroll
    for (int ks = 0; ks < 96; ks += 32) {
      bf16x8 af[4], bfr[4];
#pragma unroll
      for (int mt = 0; mt < 4; ++mt)
        af[mt] = *(const bf16x8*)&As[(wr * 64 + mt * 16 + mrow) * LDW + ks + kq];
#pragma unroll
      for (int nt = 0; nt < 4; ++nt)
        bfr[nt] = *(const bf16x8*)&Bs[(wc * 64 + nt * 16 + mrow) * LDW + ks + kq];
#pragma unroll
      for (int mt = 0; mt < 4; ++mt)
#pragma unroll
        for (int nt = 0; nt < 4; ++nt)
          acc[mt][nt] = __builtin_amdgcn_mfma_f32_16x16x32_bf16(af[mt], bfr[nt], acc[mt][nt], 0, 0, 0);
    }
    __syncthreads();
  }

  // epilogue: C/D layout col = lane&15, row = (lane>>4)*4 + reg
  const int rq = (lane >> 4) * 4;
  if (splits == 1) {
#pragma unroll
    for (int mt = 0; mt < 4; ++mt)
#pragma unroll
      for (int nt = 0; nt < 4; ++nt) {
        int colg = nbase + wc * 64 + nt * 16 + mrow;
#pragma unroll
        for (int r = 0; r < 4; ++r) {
          int rowg = mbase + wr * 64 + mt * 16 + rq + r;
          out[(size_t)rowg * NOUT + colg] = acc[mt][nt][r];
        }
      }
    return;
  }
#pragma unroll
  for (int mt = 0; mt < 4; ++mt)
#pragma unroll
    for (int nt = 0; nt < 4; ++nt) {
      int colg = nbase + wc * 64 + nt * 16 + mrow;
#pragma unroll
      for (int r = 0; r < 4; ++r) {
        int rowg = mbase + wr * 64 + mt * 16 + rq + r;
        part[((size_t)split * BATCH + rowg) * NOUT + colg] = f2bf(acc[mt][nt][r]);
      }
    }
}

// K3: out = sum over SPLITS bf16 partials (coalesced ushort8 loads)
__global__ __launch_bounds__(256) void k_reduce(const unsigned short* __restrict__ part,
                                                float* __restrict__ out) {
  int t = blockIdx.x * 256 + threadIdx.x;  // ushort8 index, 65536 total
  const ushort8* pv = (const ushort8*)part;
  float s[8] = {};
#pragma unroll
  for (int sp = 0; sp < SPLITS; ++sp) {
    ushort8 v = pv[(size_t)sp * (BATCH * NOUT / 8) + t];
#pragma unroll
    for (int e = 0; e < 8; ++e) s[e] += bf2f(v[e]);
  }
  f32x4 lo = { s[0], s[1], s[2], s[3] };
  f32x4 hi = { s[4], s[5], s[6], s[7] };
  ((f32x4*)out)[t * 2]     = lo;
  ((f32x4*)out)[t * 2 + 1] = hi;
}

extern "C" void kernel_launch(void* const* d_in, const int* in_sizes, int n_in,
                              void* d_out, int out_size, void* d_ws, size_t ws_size,
                              hipStream_t stream) {
  const float* x = (const float*)d_in[0];
  const float* c = (const float*)d_in[1];
  const float* w = (const float*)d_in[2];
  float* out = (float*)d_out;

  unsigned short* Bt = (unsigned short*)d_ws;
  size_t off_part = (size_t)NOUT * KDIM * 2;                 // 6.3 MB
  unsigned short* part = (unsigned short*)((char*)d_ws + off_part);
  size_t need = off_part + (size_t)SPLITS * BATCH * NOUT * 2;

  k_prep<<<dim3(512), 256, 0, stream>>>(c, w, Bt);
  if (ws_size >= need) {
    k_fused<<<dim3(8, 4, SPLITS), 256, 0, stream>>>(x, Bt, part, out, SPLITS, IPS);
    k_reduce<<<dim3((BATCH * NOUT / 8) / 256), 256, 0, stream>>>(part, out);
  } else {
    // fallback: single-pass straight to out (needs only Bt in ws)
    k_fused<<<dim3(8, 4, 1), 256, 0, stream>>>(x, Bt, part, out, 1, NIN);
  }
}